// Round 9
// baseline (49.632 us; speedup 1.0000x reference)
//
#include <hip/hip_runtime.h>
#include <hip/hip_bf16.h>
#include <stdint.h>

// Problem constants (from reference)
#define N_SAMP 16384
#define DCONT  64
#define DCAT   2000
#define EMB    64
#define K_CAT_PAD 2048          // 64 bit-words per row (permuted k ordering)
#define K_PAD     2112          // + 64 continuous K at the end of B
#define BM 32                   // rows per block in fm_kernel
#define BM_OFF 270336           // byte offset of bitmask in d_ws (64*2112*2 bytes of B first)

typedef short bf16x8 __attribute__((ext_vector_type(8)));
typedef float f32x4  __attribute__((ext_vector_type(4)));

__device__ __forceinline__ uint16_t f2bf(float f) {
    union { float f; uint32_t u; } v; v.f = f;
    uint32_t r = v.u + 0x7FFFu + ((v.u >> 16) & 1u);   // RNE
    return (uint16_t)(r >> 16);
}
__device__ __forceinline__ uint32_t pack2f(float a, float b) {
    return (uint32_t)f2bf(a) | ((uint32_t)f2bf(b) << 16);
}

// Build B_T[c][p] (bf16), c in [0,64), p in [0,2112):
//   p < 2048 : permuted cat index. Bit b of mask word W maps to
//              k_cat = 256*(W>>3) + 128*(W&1) + 4*b + ((W>>1)&3)   (p = 32W + b)
//              (matches the int4+ballot packing in compress_kernel; validated R8)
//   p >= 2048: W_cont[p-2048][c]
__global__ void build_b_kernel(const float* __restrict__ Wcont,
                               const float* __restrict__ Wcat,
                               uint16_t* __restrict__ Bws) {
    int p = blockIdx.x * 64 + threadIdx.x;   // 0..2111, coalesced writes along p
    int c = blockIdx.y;
    float v = 0.f;
    if (p < K_CAT_PAD) {
        int W = p >> 5, b = p & 31;
        int kc = 256 * (W >> 3) + 128 * (W & 1) + 4 * b + ((W >> 1) & 3);
        if (kc < DCAT) v = Wcat[(long)kc * EMB + c];
    } else {
        v = Wcont[(long)(p - K_CAT_PAD) * EMB + c];
    }
    Bws[(long)c * K_PAD + p] = f2bf(v);
}

// Stage A: compress xcat (131 MB int32) -> permuted bitmask [N][64 words] (4 MB).
// Pure streamer: wave reads 1 KB contiguous per int4 instruction (coalesced,
// rows are 64B-aligned: 2000*4 = 8000 % 64 == 0), 4 ballots + select tree per
// chunk leave lane L holding word L; one coalesced 256B store per row.
// 2048 blocks x 256 thr = 32 waves/CU, 0 LDS, low VGPR -> max TLP.
__global__ __launch_bounds__(256, 8)
void compress_kernel(const int* __restrict__ xcat, uint32_t* __restrict__ bm) {
    const int gw   = (blockIdx.x * 256 + threadIdx.x) >> 6;  // global wave id 0..8191
    const int lane = threadIdx.x & 63;
    #pragma unroll 1
    for (int rr = 0; rr < 2; ++rr) {
        const int row = gw * 2 + rr;
        const int* rp = xcat + (long)row * DCAT + lane * 4;
        uint32_t word = 0;
        #pragma unroll
        for (int i = 0; i < 8; ++i) {
            int4 v = make_int4(0, 0, 0, 0);
            if (i < 7 || lane < 52)                      // chunk 7 tail: k>=2000 -> 0
                v = *(const int4*)(rp + i * 256);        // contiguous 1KB per wave
            unsigned long long b0 = __ballot(v.x != 0);
            unsigned long long b1 = __ballot(v.y != 0);
            unsigned long long b2 = __ballot(v.z != 0);
            unsigned long long b3 = __ballot(v.w != 0);
            unsigned long long t0 = ((lane >> 1) & 1) ? b1 : b0;
            unsigned long long t1 = ((lane >> 1) & 1) ? b3 : b2;
            unsigned long long t  = ((lane >> 2) & 1) ? t1 : t0;
            uint32_t val = (lane & 1) ? (uint32_t)(t >> 32) : (uint32_t)t;
            word = (i == (lane >> 3)) ? val : word;      // lane L ends with word L
        }
        bm[(long)row * 64 + lane] = word;
    }
}

struct BFrag { bf16x8 b0, b1, b2, b3; };       // 4 col-frags

__global__ __launch_bounds__(256, 4)
void fm_kernel(const float* __restrict__ xc,
               const uint32_t* __restrict__ bm,
               const uint16_t* __restrict__ Bws,
               float* __restrict__ out) {
    // 4 waves/block; each wave: SAME 32 rows, its own K-quarter (512 cat k = 16 words).
    // A-operand comes from the bitmask (64B/row), expanded in-register.
    __shared__ float part[4][BM][EMB];         // 32 KiB

    const int tid  = threadIdx.x;
    const int w    = tid >> 6;
    const int lane = tid & 63;
    const int g    = lane >> 4;
    const int lr   = lane & 15;
    const int r0   = blockIdx.x * BM;

    f32x4 acc[2][4] = { { {0,0,0,0},{0,0,0,0},{0,0,0,0},{0,0,0,0} },
                        { {0,0,0,0},{0,0,0,0},{0,0,0,0},{0,0,0,0} } };

    const int kw = w * 512;                    // this wave's cat k-range start
    const uint16_t* bP = Bws + (long)lr * K_PAD;

    // --- load this wave's bitmask slice: 16 words per row, 2 rows
    const uint32_t* bmP0 = bm + (long)(r0 + lr) * 64 + w * 16;
    const uint32_t* bmP1 = bm + (long)(r0 + 16 + lr) * 64 + w * 16;
    int4 m0[4], m1[4];
    #pragma unroll
    for (int q = 0; q < 4; ++q) {
        m0[q] = *(const int4*)(bmP0 + q * 4);
        m1[q] = *(const int4*)(bmP1 + q * 4);
    }

    auto loadB = [&](int kbase) -> BFrag {
        BFrag f;
        const int kg = kbase + g * 8;
        f.b0 = *(const bf16x8*)(bP + 0 * 16 * K_PAD + kg);
        f.b1 = *(const bf16x8*)(bP + 1 * 16 * K_PAD + kg);
        f.b2 = *(const bf16x8*)(bP + 2 * 16 * K_PAD + kg);
        f.b3 = *(const bf16x8*)(bP + 3 * 16 * K_PAD + kg);
        return f;
    };
    // expand 8 bits (byte g of word) -> 8 bf16 {0,1}
    auto expand = [&](uint32_t word) -> bf16x8 {
        const uint32_t b = (word >> (g * 8)) & 0xFFu;
        union { uint32_t u[4]; bf16x8 v; } cv;
        #pragma unroll
        for (int j = 0; j < 4; ++j) {
            const uint32_t b0 = (b >> (2 * j)) & 1u;
            const uint32_t b1 = (b >> (2 * j + 1)) & 1u;
            cv.u[j] = (b0 + (b1 << 16)) * 0x3F80u;
        }
        return cv.v;
    };
    auto mmac = [&](bf16x8 af0, bf16x8 af1, const BFrag& B) {
        acc[0][0] = __builtin_amdgcn_mfma_f32_16x16x32_bf16(af0, B.b0, acc[0][0], 0, 0, 0);
        acc[0][1] = __builtin_amdgcn_mfma_f32_16x16x32_bf16(af0, B.b1, acc[0][1], 0, 0, 0);
        acc[0][2] = __builtin_amdgcn_mfma_f32_16x16x32_bf16(af0, B.b2, acc[0][2], 0, 0, 0);
        acc[0][3] = __builtin_amdgcn_mfma_f32_16x16x32_bf16(af0, B.b3, acc[0][3], 0, 0, 0);
        acc[1][0] = __builtin_amdgcn_mfma_f32_16x16x32_bf16(af1, B.b0, acc[1][0], 0, 0, 0);
        acc[1][1] = __builtin_amdgcn_mfma_f32_16x16x32_bf16(af1, B.b1, acc[1][1], 0, 0, 0);
        acc[1][2] = __builtin_amdgcn_mfma_f32_16x16x32_bf16(af1, B.b2, acc[1][2], 0, 0, 0);
        acc[1][3] = __builtin_amdgcn_mfma_f32_16x16x32_bf16(af1, B.b3, acc[1][3], 0, 0, 0);
    };

    // --- main loop: 16 K-steps of 32; B 2-deep register pipeline; no barriers
    BFrag bb0 = loadB(kw), bb1 = loadB(kw + 32);
    #pragma unroll
    for (int s = 0; s < 16; ++s) {
        const int q = s >> 2, r = s & 3;
        uint32_t w0, w1;
        // static component select (fully unrolled, no scratch)
        w0 = (r == 0) ? m0[q].x : (r == 1) ? m0[q].y : (r == 2) ? m0[q].z : m0[q].w;
        w1 = (r == 0) ? m1[q].x : (r == 1) ? m1[q].y : (r == 2) ? m1[q].z : m1[q].w;
        bf16x8 af0 = expand(w0);
        bf16x8 af1 = expand(w1);
        __builtin_amdgcn_sched_barrier(0);
        if (s & 1) { mmac(af0, af1, bb1); if (s + 2 < 16) bb1 = loadB(kw + (s + 2) * 32); }
        else       { mmac(af0, af1, bb0); if (s + 2 < 16) bb0 = loadB(kw + (s + 2) * 32); }
        __builtin_amdgcn_sched_barrier(0);
    }

    // --- continuous part: waves 2,3 take one 32-wide K-step each
    if (w >= 2) {
        const int cs = w - 2;
        const float* xP0 = xc + (long)(r0 + lr) * DCONT + cs * 32 + g * 8;
        const float* xP1 = xc + (long)(r0 + 16 + lr) * DCONT + cs * 32 + g * 8;
        float4 x0 = *(const float4*)(xP0);
        float4 x1 = *(const float4*)(xP0 + 4);
        float4 x2 = *(const float4*)(xP1);
        float4 x3 = *(const float4*)(xP1 + 4);
        BFrag bc = loadB(K_CAT_PAD + cs * 32);
        union { uint32_t u[4]; bf16x8 v; } c0, c1;
        c0.u[0] = pack2f(x0.x, x0.y); c0.u[1] = pack2f(x0.z, x0.w);
        c0.u[2] = pack2f(x1.x, x1.y); c0.u[3] = pack2f(x1.z, x1.w);
        c1.u[0] = pack2f(x2.x, x2.y); c1.u[1] = pack2f(x2.z, x2.w);
        c1.u[2] = pack2f(x3.x, x3.y); c1.u[3] = pack2f(x3.z, x3.w);
        mmac(c0.v, c1.v, bc);
    }

    // --- epilogue: combine 4 wave-partials; out[r] = 0.5*||s_row||^2
    // lane (g,lr): rows rf*16 + g*4 + r, col n*16 + lr
    #pragma unroll
    for (int rf = 0; rf < 2; ++rf)
        #pragma unroll
        for (int n = 0; n < 4; ++n)
            #pragma unroll
            for (int r = 0; r < 4; ++r)
                part[w][rf * 16 + g * 4 + r][n * 16 + lr] = acc[rf][n][r];
    __syncthreads();

    const int row = tid >> 3;           // 0..31
    const int c0i = (tid & 7) * 8;      // 8 cols per thread
    float p = 0.f;
    #pragma unroll
    for (int h = 0; h < 2; ++h) {
        float4 v0 = *(const float4*)&part[0][row][c0i + h * 4];
        float4 v1 = *(const float4*)&part[1][row][c0i + h * 4];
        float4 v2 = *(const float4*)&part[2][row][c0i + h * 4];
        float4 v3 = *(const float4*)&part[3][row][c0i + h * 4];
        float sx = v0.x + v1.x + v2.x + v3.x;
        float sy = v0.y + v1.y + v2.y + v3.y;
        float sz = v0.z + v1.z + v2.z + v3.z;
        float sw_ = v0.w + v1.w + v2.w + v3.w;
        p += sx * sx + sy * sy + sz * sz + sw_ * sw_;
    }
    p += __shfl_xor(p, 1);
    p += __shfl_xor(p, 2);
    p += __shfl_xor(p, 4);
    if ((tid & 7) == 0) out[r0 + row] = 0.5f * p;
}

extern "C" void kernel_launch(void* const* d_in, const int* in_sizes, int n_in,
                              void* d_out, int out_size, void* d_ws, size_t ws_size,
                              hipStream_t stream) {
    const float* xc    = (const float*)d_in[0];   // data_continuous [N,64] f32
    const int*   xcat  = (const int*)d_in[1];     // data_category   [N,2000] i32
    const float* Wcont = (const float*)d_in[2];   // [64,64] f32
    const float* Wcat  = (const float*)d_in[3];   // [2000,64] f32
    uint16_t* Bws = (uint16_t*)d_ws;              // B_T[64][2112] bf16 = 264 KiB
    uint32_t* bm  = (uint32_t*)((char*)d_ws + BM_OFF);  // bitmask [N][64] = 4 MiB
    float* outp = (float*)d_out;

    build_b_kernel<<<dim3(K_PAD / 64, EMB), 64, 0, stream>>>(Wcont, Wcat, Bws);
    compress_kernel<<<2048, 256, 0, stream>>>(xcat, bm);
    fm_kernel<<<N_SAMP / BM, 256, 0, stream>>>(xc, bm, Bws, outp);
}

// Round 10
// 35.429 us; speedup vs baseline: 1.4009x; 1.4009x over previous
//
#include <hip/hip_runtime.h>
#include <hip/hip_bf16.h>
#include <stdint.h>

// Problem constants (from reference)
#define N_SAMP 16384
#define DCONT  64
#define DCAT   2000
#define EMB    64
#define BM 32                   // rows per block
#define NT_TOT 66               // 64 cat K-steps of 32 (permuted) + 2 cont steps

typedef short bf16x8 __attribute__((ext_vector_type(8)));
typedef float f32x4  __attribute__((ext_vector_type(4)));

__device__ __forceinline__ uint16_t f2bf(float f) {
    union { float f; uint32_t u; } v; v.f = f;
    uint32_t r = v.u + 0x7FFFu + ((v.u >> 16) & 1u);   // RNE
    return (uint16_t)(r >> 16);
}
__device__ __forceinline__ uint32_t pack2f(float a, float b) {
    return (uint32_t)f2bf(a) | ((uint32_t)f2bf(b) << 16);
}

// Build B in MFMA FRAGMENT ORDER: BF[t][n][lane] = 8 bf16 (16 B).
// Step t, col-frag n, lane (g=lane>>4, lr=lane&15) holds col c=n*16+lr,
// permuted-k p = t*32 + g*8 + j (j=0..7).
//   p < 2048 : cat. Bit b of mask word W (p=32W+b) maps to
//              kc = 256*(W>>3) + 128*(W&1) + 4*b + ((W>>1)&3)  [validated R8/R9]
//   p >= 2048: W_cont[p-2048][c]
__global__ void build_bfrag_kernel(const float* __restrict__ Wcont,
                                   const float* __restrict__ Wcat,
                                   uint16_t* __restrict__ BF) {
    const int t = blockIdx.x, n = blockIdx.y;
    const int lane = threadIdx.x;
    const int g = lane >> 4, lr = lane & 15;
    const int c = n * 16 + lr;
    uint16_t vals[8];
    #pragma unroll
    for (int j = 0; j < 8; ++j) {
        const int p = t * 32 + g * 8 + j;
        float v = 0.f;
        if (p < 2048) {
            const int W = p >> 5, b = p & 31;
            const int kc = 256 * (W >> 3) + 128 * (W & 1) + 4 * b + ((W >> 1) & 3);
            if (kc < DCAT) v = Wcat[(long)kc * EMB + c];
        } else {
            v = Wcont[(long)(p - 2048) * EMB + c];
        }
        vals[j] = f2bf(v);
    }
    *(int4*)(BF + ((long)(t * 4 + n) * 64 + lane) * 8) = *(const int4*)vals;
}

struct BFrag { bf16x8 b0, b1, b2, b3; };       // 4 col-frags, contiguous 4KB in BF

__global__ __launch_bounds__(256, 2)
void fm_fused(const float* __restrict__ xc,
              const int*   __restrict__ xcat,
              const uint16_t* __restrict__ BF,
              float* __restrict__ out) {
    // Phase 1: each wave compresses 8 rows of xcat (coalesced int4 + ballot)
    //          into LDS bitmask [32][68]  (validated R8).
    // Phase 2: bitmask MFMA loop; B loads are CONTIGUOUS 1KB fragment reads.
    __shared__ uint32_t smem[4 * BM * EMB];    // 32 KB (mask overlay, then part)

    const int tid  = threadIdx.x;
    const int w    = tid >> 6;
    const int lane = tid & 63;
    const int g    = lane >> 4;
    const int lr   = lane & 15;
    const int r0   = blockIdx.x * BM;

    // ---- Phase 1: compress 32 rows -> LDS masks
    #pragma unroll 1
    for (int rr = 0; rr < 8; ++rr) {
        const int row = w * 8 + rr;                       // 0..31 in block
        const int* rp = xcat + (long)(r0 + row) * DCAT + lane * 4;
        uint32_t word = 0;
        #pragma unroll
        for (int i = 0; i < 8; ++i) {
            int4 v = make_int4(0, 0, 0, 0);
            if (i < 7 || lane < 52)                       // k>=2000 -> 0
                v = *(const int4*)(rp + i * 256);         // contiguous 1KB/wave
            unsigned long long b0 = __ballot(v.x != 0);
            unsigned long long b1 = __ballot(v.y != 0);
            unsigned long long b2 = __ballot(v.z != 0);
            unsigned long long b3 = __ballot(v.w != 0);
            unsigned long long t0 = ((lane >> 1) & 1) ? b1 : b0;
            unsigned long long t1 = ((lane >> 1) & 1) ? b3 : b2;
            unsigned long long t  = ((lane >> 2) & 1) ? t1 : t0;
            uint32_t val = (lane & 1) ? (uint32_t)(t >> 32) : (uint32_t)t;
            word = (i == (lane >> 3)) ? val : word;       // lane L ends with word L
        }
        smem[row * 68 + lane] = word;
    }
    __syncthreads();

    // ---- this wave's mask slice: words w*16..+16 of rows lr and 16+lr
    int4 m0[4], m1[4];
    #pragma unroll
    for (int q = 0; q < 4; ++q) {
        m0[q] = *(const int4*)&smem[lr * 68 + w * 16 + q * 4];
        m1[q] = *(const int4*)&smem[(16 + lr) * 68 + w * 16 + q * 4];
    }
    __syncthreads();                                      // masks dead; smem -> part

    f32x4 acc[2][4] = { { {0,0,0,0},{0,0,0,0},{0,0,0,0},{0,0,0,0} },
                        { {0,0,0,0},{0,0,0,0},{0,0,0,0},{0,0,0,0} } };

    auto loadBF = [&](int t) -> BFrag {
        const uint16_t* base = BF + (long)t * 2048 + lane * 8;   // frag-ordered
        BFrag f;
        f.b0 = *(const bf16x8*)(base);                            // 1KB contiguous
        f.b1 = *(const bf16x8*)(base + 512);
        f.b2 = *(const bf16x8*)(base + 1024);
        f.b3 = *(const bf16x8*)(base + 1536);
        return f;
    };
    // expand 8 bits (byte g of word) -> 8 bf16 {0,1}
    auto expand = [&](uint32_t word) -> bf16x8 {
        const uint32_t b = (word >> (g * 8)) & 0xFFu;
        union { uint32_t u[4]; bf16x8 v; } cv;
        #pragma unroll
        for (int j = 0; j < 4; ++j) {
            const uint32_t b0 = (b >> (2 * j)) & 1u;
            const uint32_t b1 = (b >> (2 * j + 1)) & 1u;
            cv.u[j] = (b0 + (b1 << 16)) * 0x3F80u;
        }
        return cv.v;
    };
    auto mmac = [&](bf16x8 af0, bf16x8 af1, const BFrag& B) {
        acc[0][0] = __builtin_amdgcn_mfma_f32_16x16x32_bf16(af0, B.b0, acc[0][0], 0, 0, 0);
        acc[0][1] = __builtin_amdgcn_mfma_f32_16x16x32_bf16(af0, B.b1, acc[0][1], 0, 0, 0);
        acc[0][2] = __builtin_amdgcn_mfma_f32_16x16x32_bf16(af0, B.b2, acc[0][2], 0, 0, 0);
        acc[0][3] = __builtin_amdgcn_mfma_f32_16x16x32_bf16(af0, B.b3, acc[0][3], 0, 0, 0);
        acc[1][0] = __builtin_amdgcn_mfma_f32_16x16x32_bf16(af1, B.b0, acc[1][0], 0, 0, 0);
        acc[1][1] = __builtin_amdgcn_mfma_f32_16x16x32_bf16(af1, B.b1, acc[1][1], 0, 0, 0);
        acc[1][2] = __builtin_amdgcn_mfma_f32_16x16x32_bf16(af1, B.b2, acc[1][2], 0, 0, 0);
        acc[1][3] = __builtin_amdgcn_mfma_f32_16x16x32_bf16(af1, B.b3, acc[1][3], 0, 0, 0);
    };

    // ---- main loop: 16 K-steps; B 2-deep register pipeline; no barriers
    const int t0i = w * 16;
    BFrag bb0 = loadBF(t0i), bb1 = loadBF(t0i + 1);
    #pragma unroll
    for (int s = 0; s < 16; ++s) {
        const int q = s >> 2, r = s & 3;
        uint32_t w0, w1;
        w0 = (r == 0) ? m0[q].x : (r == 1) ? m0[q].y : (r == 2) ? m0[q].z : m0[q].w;
        w1 = (r == 0) ? m1[q].x : (r == 1) ? m1[q].y : (r == 2) ? m1[q].z : m1[q].w;
        bf16x8 af0 = expand(w0);
        bf16x8 af1 = expand(w1);
        __builtin_amdgcn_sched_barrier(0);
        if (s & 1) { mmac(af0, af1, bb1); if (s + 2 < 16) bb1 = loadBF(t0i + s + 2); }
        else       { mmac(af0, af1, bb0); if (s + 2 < 16) bb0 = loadBF(t0i + s + 2); }
        __builtin_amdgcn_sched_barrier(0);
    }

    // ---- continuous part: waves 2,3 take steps t=64,65
    if (w >= 2) {
        const int cs = w - 2;
        const float* xP0 = xc + (long)(r0 + lr) * DCONT + cs * 32 + g * 8;
        const float* xP1 = xc + (long)(r0 + 16 + lr) * DCONT + cs * 32 + g * 8;
        float4 x0 = *(const float4*)(xP0);
        float4 x1 = *(const float4*)(xP0 + 4);
        float4 x2 = *(const float4*)(xP1);
        float4 x3 = *(const float4*)(xP1 + 4);
        BFrag bc = loadBF(64 + cs);
        union { uint32_t u[4]; bf16x8 v; } c0, c1;
        c0.u[0] = pack2f(x0.x, x0.y); c0.u[1] = pack2f(x0.z, x0.w);
        c0.u[2] = pack2f(x1.x, x1.y); c0.u[3] = pack2f(x1.z, x1.w);
        c1.u[0] = pack2f(x2.x, x2.y); c1.u[1] = pack2f(x2.z, x2.w);
        c1.u[2] = pack2f(x3.x, x3.y); c1.u[3] = pack2f(x3.z, x3.w);
        mmac(c0.v, c1.v, bc);
    }

    // ---- epilogue: combine 4 wave-partials; out[r] = 0.5*||s_row||^2
    #pragma unroll
    for (int rf = 0; rf < 2; ++rf)
        #pragma unroll
        for (int n = 0; n < 4; ++n)
            #pragma unroll
            for (int r = 0; r < 4; ++r)
                ((float*)smem)[(w * BM + rf * 16 + g * 4 + r) * EMB + n * 16 + lr] = acc[rf][n][r];
    __syncthreads();

    const int row = tid >> 3;           // 0..31
    const int c0i = (tid & 7) * 8;      // 8 cols per thread
    float p = 0.f;
    #pragma unroll
    for (int h = 0; h < 2; ++h) {
        float4 v0 = *(const float4*)&((float*)smem)[(0 * BM + row) * EMB + c0i + h * 4];
        float4 v1 = *(const float4*)&((float*)smem)[(1 * BM + row) * EMB + c0i + h * 4];
        float4 v2 = *(const float4*)&((float*)smem)[(2 * BM + row) * EMB + c0i + h * 4];
        float4 v3 = *(const float4*)&((float*)smem)[(3 * BM + row) * EMB + c0i + h * 4];
        float sx = v0.x + v1.x + v2.x + v3.x;
        float sy = v0.y + v1.y + v2.y + v3.y;
        float sz = v0.z + v1.z + v2.z + v3.z;
        float sw_ = v0.w + v1.w + v2.w + v3.w;
        p += sx * sx + sy * sy + sz * sz + sw_ * sw_;
    }
    p += __shfl_xor(p, 1);
    p += __shfl_xor(p, 2);
    p += __shfl_xor(p, 4);
    if ((tid & 7) == 0) out[r0 + row] = 0.5f * p;
}

extern "C" void kernel_launch(void* const* d_in, const int* in_sizes, int n_in,
                              void* d_out, int out_size, void* d_ws, size_t ws_size,
                              hipStream_t stream) {
    const float* xc    = (const float*)d_in[0];   // data_continuous [N,64] f32
    const int*   xcat  = (const int*)d_in[1];     // data_category   [N,2000] i32
    const float* Wcont = (const float*)d_in[2];   // [64,64] f32
    const float* Wcat  = (const float*)d_in[3];   // [2000,64] f32
    uint16_t* BF = (uint16_t*)d_ws;               // fragment-ordered B: 66*4*64*16B = 270 KiB
    float* outp = (float*)d_out;

    build_bfrag_kernel<<<dim3(NT_TOT, 4), 64, 0, stream>>>(Wcont, Wcat, BF);
    fm_fused<<<N_SAMP / BM, 256, 0, stream>>>(xc, xcat, BF, outp);
}